// Round 2
// baseline (308.050 us; speedup 1.0000x reference)
//
#include <hip/hip_runtime.h>
#include <cstdint>
#include <cstddef>

typedef unsigned short u16;
using short8 = __attribute__((ext_vector_type(8))) short;
using f32x4  = __attribute__((ext_vector_type(4))) float;

constexpr int Bc = 4, Sc = 1024, Dc = 1024, Hc = 16;
constexpr int N3 = 3 * Dc;  // 3072
// Penalty scale: must (a) underflow exp() to exactly 0 when a key is masked
// relative to an unmasked max, (b) be small enough that score differences
// survive fp32 subtraction (ulp(1024)=1.2e-4), matching the f64 np reference's
// behavior at -1e12 (ulp(1e12)_f64 = 1.2e-4, exp(-1e12) underflows to 0).
constexpr float PEN = 1024.0f;

__device__ __forceinline__ u16 f2bf(float f) {
  union { float f; uint32_t u; } v; v.f = f;
  return (u16)((v.u + 0x7fffu + ((v.u >> 16) & 1u)) >> 16);
}

// WT[n][k] = bf16(W[k][n]), 1024x1024
__global__ __launch_bounds__(256) void transpose_cvt(const float* __restrict__ W,
                                                     u16* __restrict__ WT) {
  __shared__ float t[32][33];
  int bx = blockIdx.x * 32, by = blockIdx.y * 32;
  int tx = threadIdx.x & 31, ty = threadIdx.x >> 5;  // ty 0..7
  for (int i = 0; i < 32; i += 8)
    t[ty + i][tx] = W[(size_t)(by + ty + i) * 1024 + bx + tx];
  __syncthreads();
  for (int i = 0; i < 32; i += 8)
    WT[(size_t)(bx + ty + i) * 1024 + by + tx] = f2bf(t[tx][ty + i]);
}

// C[4096][3072] = bf16( [q|k|v][4096][1024] . WT3^T + bias ), column block picks input
__global__ __launch_bounds__(256) void gemm_qkv(
    const float* __restrict__ Aq, const float* __restrict__ Ak,
    const float* __restrict__ Av, const u16* __restrict__ BT,
    const float* __restrict__ bq, const float* __restrict__ bk,
    const float* __restrict__ bv, u16* __restrict__ C) {
  const int n0 = blockIdx.x * 128, m0 = blockIdx.y * 128;
  const int seg = n0 >> 10;
  const float* A    = seg == 0 ? Aq : seg == 1 ? Ak : Av;
  const float* bias = seg == 0 ? bq : seg == 1 ? bk : bv;

  __shared__ u16 As[128][40];  // +8 pad: row stride 80B, 16B-aligned, no pow2 bank stride
  __shared__ u16 Bs[128][40];

  const int t = threadIdx.x, w = t >> 6, lane = t & 63;
  const int q4 = lane >> 4, lm = lane & 15;
  const int wm = (w >> 1) * 64, wn = (w & 1) * 64;
  const int rowA0 = t >> 2, colc = (t & 3) * 8;

  f32x4 acc[4][4] = {};

  for (int k0 = 0; k0 < 1024; k0 += 32) {
    __syncthreads();
    for (int half = 0; half < 2; ++half) {
      int row = rowA0 + half * 64;
      const float* ap = &A[(size_t)(m0 + row) * 1024 + k0 + colc];
      float4 x = *(const float4*)ap;
      float4 y = *(const float4*)(ap + 4);
      u16 tmp[8] = {f2bf(x.x), f2bf(x.y), f2bf(x.z), f2bf(x.w),
                    f2bf(y.x), f2bf(y.y), f2bf(y.z), f2bf(y.w)};
      *(uint4*)&As[row][colc] = *(const uint4*)tmp;
      *(uint4*)&Bs[row][colc] =
          *(const uint4*)&BT[(size_t)(n0 + row) * 1024 + k0 + colc];
    }
    __syncthreads();
    short8 af[4], bf[4];
    for (int mi = 0; mi < 4; ++mi)
      af[mi] = *(const short8*)&As[wm + mi * 16 + lm][q4 * 8];
    for (int ni = 0; ni < 4; ++ni)
      bf[ni] = *(const short8*)&Bs[wn + ni * 16 + lm][q4 * 8];
    for (int mi = 0; mi < 4; ++mi)
      for (int ni = 0; ni < 4; ++ni)
        acc[mi][ni] = __builtin_amdgcn_mfma_f32_16x16x32_bf16(
            af[mi], bf[ni], acc[mi][ni], 0, 0, 0);
  }
  for (int mi = 0; mi < 4; ++mi)
    for (int ni = 0; ni < 4; ++ni)
      for (int r = 0; r < 4; ++r) {
        int row = m0 + wm + mi * 16 + q4 * 4 + r;   // C/D: row=(lane>>4)*4+reg
        int col = n0 + wn + ni * 16 + lm;           //      col=lane&15
        C[(size_t)row * N3 + col] = f2bf(acc[mi][ni][r] + bias[col & 1023]);
      }
}

// out[4096][1024] = ((O . WoT^T) + bo) * qmask[row], fp32 out
__global__ __launch_bounds__(256) void gemm_out(
    const u16* __restrict__ A, const u16* __restrict__ BT,
    const float* __restrict__ bias, const int* __restrict__ qmask,
    float* __restrict__ Cf) {
  const int n0 = blockIdx.x * 128, m0 = blockIdx.y * 128;
  __shared__ u16 As[128][40];
  __shared__ u16 Bs[128][40];
  const int t = threadIdx.x, w = t >> 6, lane = t & 63;
  const int q4 = lane >> 4, lm = lane & 15;
  const int wm = (w >> 1) * 64, wn = (w & 1) * 64;
  const int rowA0 = t >> 2, colc = (t & 3) * 8;
  f32x4 acc[4][4] = {};
  for (int k0 = 0; k0 < 1024; k0 += 32) {
    __syncthreads();
    for (int half = 0; half < 2; ++half) {
      int row = rowA0 + half * 64;
      *(uint4*)&As[row][colc] =
          *(const uint4*)&A[(size_t)(m0 + row) * 1024 + k0 + colc];
      *(uint4*)&Bs[row][colc] =
          *(const uint4*)&BT[(size_t)(n0 + row) * 1024 + k0 + colc];
    }
    __syncthreads();
    short8 af[4], bf[4];
    for (int mi = 0; mi < 4; ++mi)
      af[mi] = *(const short8*)&As[wm + mi * 16 + lm][q4 * 8];
    for (int ni = 0; ni < 4; ++ni)
      bf[ni] = *(const short8*)&Bs[wn + ni * 16 + lm][q4 * 8];
    for (int mi = 0; mi < 4; ++mi)
      for (int ni = 0; ni < 4; ++ni)
        acc[mi][ni] = __builtin_amdgcn_mfma_f32_16x16x32_bf16(
            af[mi], bf[ni], acc[mi][ni], 0, 0, 0);
  }
  for (int mi = 0; mi < 4; ++mi)
    for (int ni = 0; ni < 4; ++ni)
      for (int r = 0; r < 4; ++r) {
        int row = m0 + wm + mi * 16 + q4 * 4 + r;
        int col = n0 + wn + ni * 16 + lm;
        Cf[(size_t)row * 1024 + col] =
            (acc[mi][ni][r] + bias[col]) * (float)qmask[row];
      }
}

// Flash attention: grid (S/64, H, B); 4 waves, each a 16-row Q strip.
// Blocks containing a "fully masked" row (all causally-visible keys have
// vmask=0) must also sweep FUTURE key tiles: the reference's two -1e12
// penalties put {masked visible keys} and {unmasked future keys} at the SAME
// level, so softmax spreads over both. With PEN=1024 the uniform mask logic
// reproduces the f64 reference exactly (exp(-1024)=0 underflow; score
// differences survive fp32 subtraction at ulp(1024)=1.2e-4).
__global__ __launch_bounds__(256) void attn(const u16* __restrict__ QKV,
                                            const int* __restrict__ vmask,
                                            u16* __restrict__ O) {
  const int qt = blockIdx.x, h = blockIdx.y, b = blockIdx.z;
  const int t = threadIdx.x, w = t >> 6, lane = t & 63;
  const int q4 = lane >> 4, lm = lane & 15;

  __shared__ u16 VT[64][72];    // VT[d][s_local], stride 144B (16B-aligned rows)
  __shared__ u16 P[4][16][80];  // per-wave P strip, stride 160B
  __shared__ int prefix_any;    // any vmask=1 in [0, qt*64]?

  if (t == 0) prefix_any = 0;
  __syncthreads();
  {
    int loc = 0;
    for (int i = t; i <= qt * 64; i += 256) loc |= vmask[b * Sc + i];
    if (loc) atomicOr(&prefix_any, 1);
  }
  __syncthreads();
  const int kt_end = prefix_any ? qt : (Sc / 64 - 1);

  const size_t rowbase = (size_t)b * Sc * N3;

  // Q A-fragments: A[m=lane&15][k=(lane>>4)*8+j], direct from global
  short8 qf[2];
  {
    int sq = qt * 64 + w * 16 + lm;
    const u16* qp = &QKV[rowbase + (size_t)sq * N3 + h * 64];
    qf[0] = *(const short8*)&qp[q4 * 8];
    qf[1] = *(const short8*)&qp[32 + q4 * 8];
  }
  float m_run[4] = {-1e30f, -1e30f, -1e30f, -1e30f};
  float l_run[4] = {0.f, 0.f, 0.f, 0.f};
  f32x4 oacc[4] = {};

  const int vs = t >> 2, vd0 = (t & 3) * 16;

  for (int kt = 0; kt <= kt_end; ++kt) {
    __syncthreads();  // prev iteration's VT reads complete
    {                 // stage V^T tile
      const u16* vp =
          &QKV[rowbase + (size_t)(kt * 64 + vs) * N3 + 2048 + h * 64 + vd0];
      uint4 a = *(const uint4*)vp;
      uint4 c = *(const uint4*)(vp + 8);
      u16 tmp[16];
      *(uint4*)tmp = a;
      *(uint4*)(tmp + 8) = c;
      for (int i = 0; i < 16; ++i) VT[vd0 + i][vs] = tmp[i];
    }
    __syncthreads();

    // S = Q K^T (K B-fragments direct from global)
    f32x4 sacc[4] = {};
    for (int ni = 0; ni < 4; ++ni) {
      int sk = kt * 64 + ni * 16 + lm;
      const u16* kp = &QKV[rowbase + (size_t)sk * N3 + 1024 + h * 64];
      short8 kf0 = *(const short8*)&kp[q4 * 8];
      short8 kf1 = *(const short8*)&kp[32 + q4 * 8];
      sacc[ni] = __builtin_amdgcn_mfma_f32_16x16x32_bf16(qf[0], kf0, sacc[ni], 0, 0, 0);
      sacc[ni] = __builtin_amdgcn_mfma_f32_16x16x32_bf16(qf[1], kf1, sacc[ni], 0, 0, 0);
    }

    // masks + online softmax
    float sv[4][4];
    const int qrow0 = qt * 64 + w * 16 + q4 * 4;
    for (int ni = 0; ni < 4; ++ni) {
      int key = kt * 64 + ni * 16 + lm;
      float pen = (1.0f - (float)vmask[b * Sc + key]) * PEN;
      for (int r = 0; r < 4; ++r) {
        float x = sacc[ni][r] * 0.125f - pen;
        if (key > qrow0 + r) x -= PEN;
        sv[ni][r] = x;
      }
    }
    float alpha[4];
    for (int r = 0; r < 4; ++r) {
      float mx = fmaxf(fmaxf(sv[0][r], sv[1][r]), fmaxf(sv[2][r], sv[3][r]));
      for (int off = 1; off < 16; off <<= 1)
        mx = fmaxf(mx, __shfl_xor(mx, off, 64));
      float mn = fmaxf(m_run[r], mx);
      alpha[r] = expf(m_run[r] - mn);
      m_run[r] = mn;
      float rs = 0.f;
      for (int ni = 0; ni < 4; ++ni) {
        float p = expf(sv[ni][r] - mn);
        sv[ni][r] = p;
        rs += p;
      }
      for (int off = 1; off < 16; off <<= 1)
        rs += __shfl_xor(rs, off, 64);
      l_run[r] = l_run[r] * alpha[r] + rs;
    }
    for (int ni = 0; ni < 4; ++ni)
      for (int r = 0; r < 4; ++r) {
        oacc[ni][r] *= alpha[r];
        P[w][q4 * 4 + r][ni * 16 + lm] = f2bf(sv[ni][r]);  // C-layout write
      }
    __syncthreads();  // P visible (cross-lane), VT still valid

    // O += P V  (P re-read in A-layout from LDS; V B-frags from VT)
    short8 pf0 = *(const short8*)&P[w][lm][q4 * 8];
    short8 pf1 = *(const short8*)&P[w][lm][32 + q4 * 8];
    for (int ni = 0; ni < 4; ++ni) {
      short8 vf0 = *(const short8*)&VT[ni * 16 + lm][q4 * 8];
      short8 vf1 = *(const short8*)&VT[ni * 16 + lm][32 + q4 * 8];
      oacc[ni] = __builtin_amdgcn_mfma_f32_16x16x32_bf16(pf0, vf0, oacc[ni], 0, 0, 0);
      oacc[ni] = __builtin_amdgcn_mfma_f32_16x16x32_bf16(pf1, vf1, oacc[ni], 0, 0, 0);
    }
  }
  for (int ni = 0; ni < 4; ++ni)
    for (int r = 0; r < 4; ++r) {
      int sc = qt * 64 + w * 16 + q4 * 4 + r;
      O[(size_t)(b * Sc + sc) * 1024 + h * 64 + ni * 16 + lm] =
          f2bf(oacc[ni][r] / l_run[r]);
    }
}

extern "C" void kernel_launch(void* const* d_in, const int* in_sizes, int n_in,
                              void* d_out, int out_size, void* d_ws, size_t ws_size,
                              hipStream_t stream) {
  (void)in_sizes; (void)n_in; (void)out_size; (void)ws_size;
  const float* q  = (const float*)d_in[0];
  const float* k  = (const float*)d_in[1];
  const float* v  = (const float*)d_in[2];
  const int* vmask = (const int*)d_in[3];
  const int* qmask = (const int*)d_in[4];
  // d_in[5] a_mask: causal tril, handled analytically
  const float* Wq = (const float*)d_in[6];
  const float* bq = (const float*)d_in[7];
  const float* Wk = (const float*)d_in[8];
  const float* bk = (const float*)d_in[9];
  const float* Wv = (const float*)d_in[10];
  const float* bv = (const float*)d_in[11];
  const float* Wo = (const float*)d_in[12];
  const float* bo = (const float*)d_in[13];

  char* ws = (char*)d_ws;
  u16* WT3  = (u16*)ws;                   // [3072][1024] bf16 (Wq^T|Wk^T|Wv^T)
  u16* WoT  = (u16*)(ws + 6291456);       // [1024][1024] bf16
  u16* QKVw = (u16*)(ws + 8388608);       // [4096][3072] bf16 (qw|kw|vw per row)
  u16* Oat  = (u16*)(ws + 33554432);      // [4096][1024] bf16 attention out

  dim3 tb(256);
  transpose_cvt<<<dim3(32, 32), tb, 0, stream>>>(Wq, WT3);
  transpose_cvt<<<dim3(32, 32), tb, 0, stream>>>(Wk, WT3 + 1024 * 1024);
  transpose_cvt<<<dim3(32, 32), tb, 0, stream>>>(Wv, WT3 + 2 * 1024 * 1024);
  transpose_cvt<<<dim3(32, 32), tb, 0, stream>>>(Wo, WoT);
  gemm_qkv<<<dim3(24, 32), tb, 0, stream>>>(q, k, v, WT3, bq, bk, bv, QKVw);
  attn<<<dim3(16, 16, 4), tb, 0, stream>>>(QKVw, vmask, Oat);
  gemm_out<<<dim3(8, 32), tb, 0, stream>>>(Oat, WoT, bo, qmask, (float*)d_out);
}